// Round 1
// baseline (5022.071 us; speedup 1.0000x reference)
//
#include <hip/hip_runtime.h>
#include <hip/hip_bf16.h>
#include <math.h>

// Problem constants
#define B_ 4
#define S_ 2048
#define D_ 1024
#define H_ 16
#define DH_ 64
#define INNER_ 1024   // H_*DH_
#define N3_ 3072      // 3*INNER_
#define ROWS_ 8192    // B_*S_

// ---------------------------------------------------------------------------
// LayerNorm: one block (256 threads) per row of 1024 floats.
// ---------------------------------------------------------------------------
__global__ __launch_bounds__(256) void ln_kernel(const float* __restrict__ x,
                                                 const float* __restrict__ gamma,
                                                 const float* __restrict__ beta,
                                                 float* __restrict__ xn) {
    const int row = blockIdx.x;
    const int tid = threadIdx.x;
    const float4 v = ((const float4*)(x + (size_t)row * D_))[tid];
    float s  = v.x + v.y + v.z + v.w;
    float ss = v.x * v.x + v.y * v.y + v.z * v.z + v.w * v.w;
    #pragma unroll
    for (int off = 32; off > 0; off >>= 1) {
        s  += __shfl_down(s, off);
        ss += __shfl_down(ss, off);
    }
    __shared__ float red[8];
    const int wave = tid >> 6, lane = tid & 63;
    if (lane == 0) { red[wave] = s; red[4 + wave] = ss; }
    __syncthreads();
    const float S  = red[0] + red[1] + red[2] + red[3];
    const float SS = red[4] + red[5] + red[6] + red[7];
    const float mu  = S * (1.0f / D_);
    const float var = SS * (1.0f / D_) - mu * mu;
    const float rs  = rsqrtf(var + 1e-5f);
    const float4 g  = ((const float4*)gamma)[tid];
    const float4 bb = ((const float4*)beta)[tid];
    float4 o;
    o.x = (v.x - mu) * rs * g.x + bb.x;
    o.y = (v.y - mu) * rs * g.y + bb.y;
    o.z = (v.z - mu) * rs * g.z + bb.z;
    o.w = (v.w - mu) * rs * g.w + bb.w;
    ((float4*)(xn + (size_t)row * D_))[tid] = o;
}

// ---------------------------------------------------------------------------
// fp32 SGEMM: C[M,N] = A[M,K] @ B[K,N] (+ bias[N]).  BM=BN=128, BK=16,
// 256 threads, 8x8 micro-tile per thread (split as 2x 4-row / 4-col halves).
// M%128==0, N%128==0, K%16==0 assumed.
// ---------------------------------------------------------------------------
__global__ __launch_bounds__(256) void sgemm_kernel(const float* __restrict__ A,
                                                    const float* __restrict__ B,
                                                    float* __restrict__ C,
                                                    int M, int N, int K,
                                                    const float* __restrict__ bias) {
    __shared__ float As[16][132];
    __shared__ float Bs[16][132];
    const int tid = threadIdx.x;
    const int tx = tid & 15;
    const int ty = tid >> 4;
    const int m0 = blockIdx.y * 128;
    const int n0 = blockIdx.x * 128;

    float acc[8][8];
    #pragma unroll
    for (int i = 0; i < 8; ++i)
        #pragma unroll
        for (int j = 0; j < 8; ++j) acc[i][j] = 0.0f;

    const int a_row = tid >> 2;         // 0..63
    const int a_k   = (tid & 3) * 4;    // 0,4,8,12

    for (int k0 = 0; k0 < K; k0 += 16) {
        // Load A tile (128x16), store transposed As[k][m]
        #pragma unroll
        for (int l = 0; l < 2; ++l) {
            const int r = a_row + l * 64;
            const float4 v = *(const float4*)(A + (size_t)(m0 + r) * K + k0 + a_k);
            As[a_k + 0][r] = v.x;
            As[a_k + 1][r] = v.y;
            As[a_k + 2][r] = v.z;
            As[a_k + 3][r] = v.w;
        }
        // Load B tile (16x128) direct
        #pragma unroll
        for (int l = 0; l < 2; ++l) {
            const int f  = tid + l * 256;     // 0..511
            const int kk = f >> 5;            // 0..15
            const int nn = (f & 31) * 4;      // 0..124
            *(float4*)(&Bs[kk][nn]) = *(const float4*)(B + (size_t)(k0 + kk) * N + n0 + nn);
        }
        __syncthreads();
        #pragma unroll
        for (int kk = 0; kk < 16; ++kk) {
            float a[8], b[8];
            *(float4*)(a)     = *(const float4*)(&As[kk][ty * 4]);
            *(float4*)(a + 4) = *(const float4*)(&As[kk][64 + ty * 4]);
            *(float4*)(b)     = *(const float4*)(&Bs[kk][tx * 4]);
            *(float4*)(b + 4) = *(const float4*)(&Bs[kk][64 + tx * 4]);
            #pragma unroll
            for (int i = 0; i < 8; ++i)
                #pragma unroll
                for (int j = 0; j < 8; ++j) acc[i][j] += a[i] * b[j];
        }
        __syncthreads();
    }

    // Epilogue
    #pragma unroll
    for (int ih = 0; ih < 2; ++ih) {
        #pragma unroll
        for (int i = 0; i < 4; ++i) {
            const int r = m0 + ih * 64 + ty * 4 + i;
            float* crow = C + (size_t)r * N + n0;
            #pragma unroll
            for (int jh = 0; jh < 2; ++jh) {
                const int c0 = jh * 64 + tx * 4;
                float4 v;
                v.x = acc[ih * 4 + i][jh * 4 + 0];
                v.y = acc[ih * 4 + i][jh * 4 + 1];
                v.z = acc[ih * 4 + i][jh * 4 + 2];
                v.w = acc[ih * 4 + i][jh * 4 + 3];
                if (bias) {
                    const float4 bv = *(const float4*)(bias + n0 + c0);
                    v.x += bv.x; v.y += bv.y; v.z += bv.z; v.w += bv.w;
                }
                *(float4*)(crow + c0) = v;
            }
        }
    }
}

// ---------------------------------------------------------------------------
// RoPE cos/sin table: [S_][32] each, accurate sincosf.
// ---------------------------------------------------------------------------
__global__ __launch_bounds__(256) void rope_table_kernel(float* __restrict__ cost,
                                                         float* __restrict__ sint) {
    const int idx = blockIdx.x * 256 + threadIdx.x;  // 0..65535
    const int s = idx >> 5;
    const int i = idx & 31;
    const float inv = powf(10000.0f, -(2.0f * (float)i) / 64.0f);
    const float f = (float)s * inv;
    float sv, cv;
    sincosf(f, &sv, &cv);
    cost[idx] = cv;
    sint[idx] = sv;
}

// ---------------------------------------------------------------------------
// RoPE apply, in-place on q and k halves of the qkv buffer.
// One thread per (row, head, d<32) pair.
// ---------------------------------------------------------------------------
__global__ __launch_bounds__(256) void rope_apply_kernel(float* __restrict__ qkv,
                                                         const float* __restrict__ cost,
                                                         const float* __restrict__ sint) {
    const int idx = blockIdx.x * 256 + threadIdx.x;  // B_*S_*H_*32
    const int d = idx & 31;
    const int h = (idx >> 5) & 15;
    const int row = idx >> 9;        // b*S_+s, 0..8191
    const int spos = row & (S_ - 1);
    const size_t base = (size_t)row * N3_ + h * 64 + d;
    const float c  = cost[spos * 32 + d];
    const float sn = sint[spos * 32 + d];
    const float q1 = qkv[base], q2 = qkv[base + 32];
    qkv[base]      = q1 * c - q2 * sn;
    qkv[base + 32] = q1 * sn + q2 * c;
    const float k1 = qkv[base + 1024], k2 = qkv[base + 1056];
    qkv[base + 1024] = k1 * c - k2 * sn;
    qkv[base + 1056] = k1 * sn + k2 * c;
}

// ---------------------------------------------------------------------------
// Flash attention (fp32): one block = 256 q-rows of one (b,h); each thread
// owns one q-row. K/V tiles 64x64 staged in LDS, broadcast reads.
// Online softmax in 32-wide column sub-tiles (keeps s[] at 32 regs).
// att layout: [b, s, h*64+d]  (= [8192, 1024] row-major).
// ---------------------------------------------------------------------------
__global__ __launch_bounds__(256) void attn_kernel(const float* __restrict__ qkv,
                                                   float* __restrict__ att) {
    __shared__ float Kt[64][64];
    __shared__ float Vt[64][64];
    const int tid = threadIdx.x;
    const int bh = blockIdx.x;
    const int b = bh >> 4;
    const int h = bh & 15;
    const int sq = blockIdx.y * 256 + tid;

    const size_t qbase = ((size_t)(b * S_ + sq)) * N3_ + h * 64;
    float q[64];
    #pragma unroll
    for (int d4 = 0; d4 < 16; ++d4) {
        const float4 v = *(const float4*)(qkv + qbase + d4 * 4);
        q[d4 * 4 + 0] = v.x * 0.125f;
        q[d4 * 4 + 1] = v.y * 0.125f;
        q[d4 * 4 + 2] = v.z * 0.125f;
        q[d4 * 4 + 3] = v.w * 0.125f;
    }
    float o[64];
    #pragma unroll
    for (int d = 0; d < 64; ++d) o[d] = 0.0f;
    float m = -1e30f, l = 0.0f;

    const size_t kvbase = ((size_t)b * S_) * N3_ + h * 64;

    for (int j0 = 0; j0 < S_; j0 += 64) {
        __syncthreads();
        #pragma unroll
        for (int ld = 0; ld < 4; ++ld) {
            const int f = tid + ld * 256;      // 0..1023
            const int jj = f >> 4;
            const int dseg = (f & 15) * 4;
            const size_t g = kvbase + (size_t)(j0 + jj) * N3_ + dseg;
            *(float4*)(&Kt[jj][dseg]) = *(const float4*)(qkv + g + 1024);
            *(float4*)(&Vt[jj][dseg]) = *(const float4*)(qkv + g + 2048);
        }
        __syncthreads();

        #pragma unroll
        for (int half = 0; half < 2; ++half) {
            float s[32];
            #pragma unroll
            for (int j = 0; j < 32; ++j) {
                const float* kr = &Kt[half * 32 + j][0];
                float p0 = 0, p1 = 0, p2 = 0, p3 = 0;
                #pragma unroll
                for (int d4 = 0; d4 < 16; ++d4) {
                    const float4 kv4 = *(const float4*)(kr + d4 * 4);
                    p0 += q[d4 * 4 + 0] * kv4.x;
                    p1 += q[d4 * 4 + 1] * kv4.y;
                    p2 += q[d4 * 4 + 2] * kv4.z;
                    p3 += q[d4 * 4 + 3] * kv4.w;
                }
                s[j] = (p0 + p1) + (p2 + p3);
            }
            float tmax = s[0];
            #pragma unroll
            for (int j = 1; j < 32; ++j) tmax = fmaxf(tmax, s[j]);
            const float mn = fmaxf(m, tmax);
            const float factor = __expf(m - mn);
            m = mn;
            float psum = 0.0f;
            #pragma unroll
            for (int j = 0; j < 32; ++j) {
                s[j] = __expf(s[j] - mn);
                psum += s[j];
            }
            l = l * factor + psum;
            #pragma unroll
            for (int d = 0; d < 64; ++d) o[d] *= factor;
            #pragma unroll
            for (int j = 0; j < 32; ++j) {
                const float* vr = &Vt[half * 32 + j][0];
                const float pj = s[j];
                #pragma unroll
                for (int d4 = 0; d4 < 16; ++d4) {
                    const float4 vv = *(const float4*)(vr + d4 * 4);
                    o[d4 * 4 + 0] += pj * vv.x;
                    o[d4 * 4 + 1] += pj * vv.y;
                    o[d4 * 4 + 2] += pj * vv.z;
                    o[d4 * 4 + 3] += pj * vv.w;
                }
            }
        }
    }

    const float inv_l = 1.0f / l;
    const size_t obase = ((size_t)(b * S_ + sq)) * INNER_ + h * 64;
    #pragma unroll
    for (int d4 = 0; d4 < 16; ++d4) {
        float4 ov;
        ov.x = o[d4 * 4 + 0] * inv_l;
        ov.y = o[d4 * 4 + 1] * inv_l;
        ov.z = o[d4 * 4 + 2] * inv_l;
        ov.w = o[d4 * 4 + 3] * inv_l;
        *(float4*)(att + obase + d4 * 4) = ov;
    }
}

// ---------------------------------------------------------------------------
// Launch
// ---------------------------------------------------------------------------
extern "C" void kernel_launch(void* const* d_in, const int* in_sizes, int n_in,
                              void* d_out, int out_size, void* d_ws, size_t ws_size,
                              hipStream_t stream) {
    const float* x        = (const float*)d_in[0];
    const float* w_qkv    = (const float*)d_in[1];
    const float* w_out    = (const float*)d_in[2];
    const float* b_out    = (const float*)d_in[3];
    const float* ln_gamma = (const float*)d_in[4];
    const float* ln_beta  = (const float*)d_in[5];
    float* out = (float*)d_out;

    float* ws = (float*)d_ws;
    float* xn   = ws;                         // 8192*1024 (reused as att)
    float* qkv  = ws + (size_t)ROWS_ * D_;    // 8192*3072
    float* cost = qkv + (size_t)ROWS_ * N3_;  // 65536
    float* sint = cost + S_ * 32;             // 65536
    float* att  = xn;                         // reuse: xn dead after qkv gemm

    // 1. LayerNorm
    ln_kernel<<<ROWS_, 256, 0, stream>>>(x, ln_gamma, ln_beta, xn);

    // 2. QKV projection: [8192,1024] @ [1024,3072]
    sgemm_kernel<<<dim3(N3_ / 128, ROWS_ / 128), 256, 0, stream>>>(
        xn, w_qkv, qkv, ROWS_, N3_, D_, nullptr);

    // 3. RoPE table + apply
    rope_table_kernel<<<(S_ * 32) / 256, 256, 0, stream>>>(cost, sint);
    rope_apply_kernel<<<(B_ * S_ * H_ * 32) / 256, 256, 0, stream>>>(qkv, cost, sint);

    // 4. Attention
    attn_kernel<<<dim3(B_ * H_, S_ / 256), 256, 0, stream>>>(qkv, att);

    // 5. Output projection + bias: [8192,1024] @ [1024,1024] + b_out
    sgemm_kernel<<<dim3(D_ / 128, ROWS_ / 128), 256, 0, stream>>>(
        att, w_out, out, ROWS_, D_, INNER_, b_out);
}

// Round 2
// 3119.155 us; speedup vs baseline: 1.6101x; 1.6101x over previous
//
#include <hip/hip_runtime.h>
#include <hip/hip_bf16.h>
#include <math.h>

// Problem constants
#define B_ 4
#define S_ 2048
#define D_ 1024
#define H_ 16
#define DH_ 64
#define INNER_ 1024   // H_*DH_
#define N3_ 3072      // 3*INNER_
#define ROWS_ 8192    // B_*S_

// ---------------------------------------------------------------------------
// LayerNorm: one block (256 threads) per row of 1024 floats.
// ---------------------------------------------------------------------------
__global__ __launch_bounds__(256) void ln_kernel(const float* __restrict__ x,
                                                 const float* __restrict__ gamma,
                                                 const float* __restrict__ beta,
                                                 float* __restrict__ xn) {
    const int row = blockIdx.x;
    const int tid = threadIdx.x;
    const float4 v = ((const float4*)(x + (size_t)row * D_))[tid];
    float s  = v.x + v.y + v.z + v.w;
    float ss = v.x * v.x + v.y * v.y + v.z * v.z + v.w * v.w;
    #pragma unroll
    for (int off = 32; off > 0; off >>= 1) {
        s  += __shfl_down(s, off);
        ss += __shfl_down(ss, off);
    }
    __shared__ float red[8];
    const int wave = tid >> 6, lane = tid & 63;
    if (lane == 0) { red[wave] = s; red[4 + wave] = ss; }
    __syncthreads();
    const float S  = red[0] + red[1] + red[2] + red[3];
    const float SS = red[4] + red[5] + red[6] + red[7];
    const float mu  = S * (1.0f / D_);
    const float var = SS * (1.0f / D_) - mu * mu;
    const float rs  = rsqrtf(var + 1e-5f);
    const float4 g  = ((const float4*)gamma)[tid];
    const float4 bb = ((const float4*)beta)[tid];
    float4 o;
    o.x = (v.x - mu) * rs * g.x + bb.x;
    o.y = (v.y - mu) * rs * g.y + bb.y;
    o.z = (v.z - mu) * rs * g.z + bb.z;
    o.w = (v.w - mu) * rs * g.w + bb.w;
    ((float4*)(xn + (size_t)row * D_))[tid] = o;
}

// ---------------------------------------------------------------------------
// fp32 SGEMM: C[M,N] = A[M,K] @ B[K,N] (+ bias[N]).  BM=BN=128, BK=16,
// 256 threads, 8x8 micro-tile per thread.
// ---------------------------------------------------------------------------
__global__ __launch_bounds__(256) void sgemm_kernel(const float* __restrict__ A,
                                                    const float* __restrict__ B,
                                                    float* __restrict__ C,
                                                    int M, int N, int K,
                                                    const float* __restrict__ bias) {
    __shared__ float As[16][132];
    __shared__ float Bs[16][132];
    const int tid = threadIdx.x;
    const int tx = tid & 15;
    const int ty = tid >> 4;
    const int m0 = blockIdx.y * 128;
    const int n0 = blockIdx.x * 128;

    float acc[8][8];
    #pragma unroll
    for (int i = 0; i < 8; ++i)
        #pragma unroll
        for (int j = 0; j < 8; ++j) acc[i][j] = 0.0f;

    const int a_row = tid >> 2;         // 0..63
    const int a_k   = (tid & 3) * 4;    // 0,4,8,12

    for (int k0 = 0; k0 < K; k0 += 16) {
        #pragma unroll
        for (int l = 0; l < 2; ++l) {
            const int r = a_row + l * 64;
            const float4 v = *(const float4*)(A + (size_t)(m0 + r) * K + k0 + a_k);
            As[a_k + 0][r] = v.x;
            As[a_k + 1][r] = v.y;
            As[a_k + 2][r] = v.z;
            As[a_k + 3][r] = v.w;
        }
        #pragma unroll
        for (int l = 0; l < 2; ++l) {
            const int f  = tid + l * 256;
            const int kk = f >> 5;
            const int nn = (f & 31) * 4;
            *(float4*)(&Bs[kk][nn]) = *(const float4*)(B + (size_t)(k0 + kk) * N + n0 + nn);
        }
        __syncthreads();
        #pragma unroll
        for (int kk = 0; kk < 16; ++kk) {
            float a[8], b[8];
            *(float4*)(a)     = *(const float4*)(&As[kk][ty * 4]);
            *(float4*)(a + 4) = *(const float4*)(&As[kk][64 + ty * 4]);
            *(float4*)(b)     = *(const float4*)(&Bs[kk][tx * 4]);
            *(float4*)(b + 4) = *(const float4*)(&Bs[kk][64 + tx * 4]);
            #pragma unroll
            for (int i = 0; i < 8; ++i)
                #pragma unroll
                for (int j = 0; j < 8; ++j) acc[i][j] += a[i] * b[j];
        }
        __syncthreads();
    }

    #pragma unroll
    for (int ih = 0; ih < 2; ++ih) {
        #pragma unroll
        for (int i = 0; i < 4; ++i) {
            const int r = m0 + ih * 64 + ty * 4 + i;
            float* crow = C + (size_t)r * N + n0;
            #pragma unroll
            for (int jh = 0; jh < 2; ++jh) {
                const int c0 = jh * 64 + tx * 4;
                float4 v;
                v.x = acc[ih * 4 + i][jh * 4 + 0];
                v.y = acc[ih * 4 + i][jh * 4 + 1];
                v.z = acc[ih * 4 + i][jh * 4 + 2];
                v.w = acc[ih * 4 + i][jh * 4 + 3];
                if (bias) {
                    const float4 bv = *(const float4*)(bias + n0 + c0);
                    v.x += bv.x; v.y += bv.y; v.z += bv.z; v.w += bv.w;
                }
                *(float4*)(crow + c0) = v;
            }
        }
    }
}

// ---------------------------------------------------------------------------
// RoPE cos/sin table: [S_][32] each.
// ---------------------------------------------------------------------------
__global__ __launch_bounds__(256) void rope_table_kernel(float* __restrict__ cost,
                                                         float* __restrict__ sint) {
    const int idx = blockIdx.x * 256 + threadIdx.x;  // 0..65535
    const int s = idx >> 5;
    const int i = idx & 31;
    const float inv = powf(10000.0f, -(2.0f * (float)i) / 64.0f);
    const float f = (float)s * inv;
    float sv, cv;
    sincosf(f, &sv, &cv);
    cost[idx] = cv;
    sint[idx] = sv;
}

// ---------------------------------------------------------------------------
// RoPE apply, in-place on q and k halves of the qkv buffer.
// ---------------------------------------------------------------------------
__global__ __launch_bounds__(256) void rope_apply_kernel(float* __restrict__ qkv,
                                                         const float* __restrict__ cost,
                                                         const float* __restrict__ sint) {
    const int idx = blockIdx.x * 256 + threadIdx.x;  // B_*S_*H_*32
    const int d = idx & 31;
    const int h = (idx >> 5) & 15;
    const int row = idx >> 9;        // b*S_+s, 0..8191
    const int spos = row & (S_ - 1);
    const size_t base = (size_t)row * N3_ + h * 64 + d;
    const float c  = cost[spos * 32 + d];
    const float sn = sint[spos * 32 + d];
    const float q1 = qkv[base], q2 = qkv[base + 32];
    qkv[base]      = q1 * c - q2 * sn;
    qkv[base + 32] = q1 * sn + q2 * c;
    const float k1 = qkv[base + 1024], k2 = qkv[base + 1056];
    qkv[base + 1024] = k1 * c - k2 * sn;
    qkv[base + 1056] = k1 * sn + k2 * c;
}

// ---------------------------------------------------------------------------
// Flash attention v2 (fp32), register-blocked.
// Block = 256 threads handles 256 q-rows of one (b,h).
// 4-lane group = 4 q-rows x full 64 dims; lane&3 picks a 16-dim slice.
// Each thread: q[4][16], o[4][16], online softmax state m[4], l[4].
// K/V staged 64x64 in LDS; each K/V slice read ONCE per j, reused for 4 rows
// (4x fewer LDS instructions than v1). QK partial dots reduced across the
// 4 slice-lanes via __shfl_xor(1|2).
// ---------------------------------------------------------------------------
__global__ __launch_bounds__(256, 2) void attn_kernel(const float* __restrict__ qkv,
                                                      float* __restrict__ att) {
    __shared__ float Kt[64][64];
    __shared__ float Vt[64][64];
    const int tid  = threadIdx.x;
    const int lane = tid & 63;
    const int wave = tid >> 6;
    const int ds   = lane & 3;        // d-slice 0..3 (dims ds*16..ds*16+15)
    const int rg   = lane >> 2;       // row group 0..15
    const int bh = blockIdx.x;
    const int b = bh >> 4;
    const int h = bh & 15;
    const int row0 = blockIdx.y * 256 + wave * 64 + rg * 4;  // 4 rows: row0..row0+3

    // Load q fragments (scaled by 1/sqrt(64))
    float q[4][16];
    #pragma unroll
    for (int r = 0; r < 4; ++r) {
        const size_t qb = ((size_t)(b * S_ + row0 + r)) * N3_ + h * 64 + ds * 16;
        #pragma unroll
        for (int i = 0; i < 4; ++i) {
            const float4 v = *(const float4*)(qkv + qb + i * 4);
            q[r][i * 4 + 0] = v.x * 0.125f;
            q[r][i * 4 + 1] = v.y * 0.125f;
            q[r][i * 4 + 2] = v.z * 0.125f;
            q[r][i * 4 + 3] = v.w * 0.125f;
        }
    }
    float o[4][16];
    #pragma unroll
    for (int r = 0; r < 4; ++r)
        #pragma unroll
        for (int d = 0; d < 16; ++d) o[r][d] = 0.0f;
    float m[4] = {-1e30f, -1e30f, -1e30f, -1e30f};
    float l[4] = {0.0f, 0.0f, 0.0f, 0.0f};

    const size_t kvbase = ((size_t)b * S_) * N3_ + h * 64;

    for (int j0 = 0; j0 < S_; j0 += 64) {
        __syncthreads();
        #pragma unroll
        for (int ld = 0; ld < 4; ++ld) {
            const int f = tid + ld * 256;      // 0..1023
            const int jj = f >> 4;
            const int dseg = (f & 15) * 4;
            const size_t g = kvbase + (size_t)(j0 + jj) * N3_ + dseg;
            *(float4*)(&Kt[jj][dseg]) = *(const float4*)(qkv + g + 1024);
            *(float4*)(&Vt[jj][dseg]) = *(const float4*)(qkv + g + 2048);
        }
        __syncthreads();

        #pragma unroll
        for (int chunk = 0; chunk < 4; ++chunk) {
            float sc[4][16];
            // ---- QK^T for 16 j's ----
            #pragma unroll
            for (int jj = 0; jj < 16; ++jj) {
                const int j = chunk * 16 + jj;
                float kv[16];
                #pragma unroll
                for (int i = 0; i < 4; ++i)
                    *(float4*)(&kv[i * 4]) = *(const float4*)(&Kt[j][ds * 16 + i * 4]);
                #pragma unroll
                for (int r = 0; r < 4; ++r) {
                    float p0 = 0, p1 = 0, p2 = 0, p3 = 0;
                    #pragma unroll
                    for (int i = 0; i < 4; ++i) {
                        p0 += q[r][i * 4 + 0] * kv[i * 4 + 0];
                        p1 += q[r][i * 4 + 1] * kv[i * 4 + 1];
                        p2 += q[r][i * 4 + 2] * kv[i * 4 + 2];
                        p3 += q[r][i * 4 + 3] * kv[i * 4 + 3];
                    }
                    sc[r][jj] = (p0 + p1) + (p2 + p3);
                }
            }
            // ---- reduce partial dots across the 4 slice-lanes ----
            #pragma unroll
            for (int r = 0; r < 4; ++r)
                #pragma unroll
                for (int jj = 0; jj < 16; ++jj) {
                    float v = sc[r][jj];
                    v += __shfl_xor(v, 1);
                    v += __shfl_xor(v, 2);
                    sc[r][jj] = v;
                }
            // ---- online softmax update (per row) ----
            #pragma unroll
            for (int r = 0; r < 4; ++r) {
                float cm = sc[r][0];
                #pragma unroll
                for (int jj = 1; jj < 16; ++jj) cm = fmaxf(cm, sc[r][jj]);
                const float mn = fmaxf(m[r], cm);
                const float fac = __expf(m[r] - mn);
                m[r] = mn;
                float ps = 0.0f;
                #pragma unroll
                for (int jj = 0; jj < 16; ++jj) {
                    sc[r][jj] = __expf(sc[r][jj] - mn);
                    ps += sc[r][jj];
                }
                l[r] = l[r] * fac + ps;
                #pragma unroll
                for (int d = 0; d < 16; ++d) o[r][d] *= fac;
            }
            // ---- PV accumulate ----
            #pragma unroll
            for (int jj = 0; jj < 16; ++jj) {
                const int j = chunk * 16 + jj;
                float vv[16];
                #pragma unroll
                for (int i = 0; i < 4; ++i)
                    *(float4*)(&vv[i * 4]) = *(const float4*)(&Vt[j][ds * 16 + i * 4]);
                #pragma unroll
                for (int r = 0; r < 4; ++r) {
                    const float pj = sc[r][jj];
                    #pragma unroll
                    for (int d = 0; d < 16; ++d) o[r][d] += pj * vv[d];
                }
            }
        }
    }

    // ---- write out ----
    #pragma unroll
    for (int r = 0; r < 4; ++r) {
        const float inv_l = 1.0f / l[r];
        const size_t ob = ((size_t)(b * S_ + row0 + r)) * INNER_ + h * 64 + ds * 16;
        #pragma unroll
        for (int i = 0; i < 4; ++i) {
            float4 ov;
            ov.x = o[r][i * 4 + 0] * inv_l;
            ov.y = o[r][i * 4 + 1] * inv_l;
            ov.z = o[r][i * 4 + 2] * inv_l;
            ov.w = o[r][i * 4 + 3] * inv_l;
            *(float4*)(att + ob + i * 4) = ov;
        }
    }
}

// ---------------------------------------------------------------------------
// Launch
// ---------------------------------------------------------------------------
extern "C" void kernel_launch(void* const* d_in, const int* in_sizes, int n_in,
                              void* d_out, int out_size, void* d_ws, size_t ws_size,
                              hipStream_t stream) {
    const float* x        = (const float*)d_in[0];
    const float* w_qkv    = (const float*)d_in[1];
    const float* w_out    = (const float*)d_in[2];
    const float* b_out    = (const float*)d_in[3];
    const float* ln_gamma = (const float*)d_in[4];
    const float* ln_beta  = (const float*)d_in[5];
    float* out = (float*)d_out;

    float* ws = (float*)d_ws;
    float* xn   = ws;                         // 8192*1024 (reused as att)
    float* qkv  = ws + (size_t)ROWS_ * D_;    // 8192*3072
    float* cost = qkv + (size_t)ROWS_ * N3_;  // 65536
    float* sint = cost + S_ * 32;             // 65536
    float* att  = xn;                         // reuse: xn dead after qkv gemm

    // 1. LayerNorm
    ln_kernel<<<ROWS_, 256, 0, stream>>>(x, ln_gamma, ln_beta, xn);

    // 2. QKV projection: [8192,1024] @ [1024,3072]
    sgemm_kernel<<<dim3(N3_ / 128, ROWS_ / 128), 256, 0, stream>>>(
        xn, w_qkv, qkv, ROWS_, N3_, D_, nullptr);

    // 3. RoPE table + apply
    rope_table_kernel<<<(S_ * 32) / 256, 256, 0, stream>>>(cost, sint);
    rope_apply_kernel<<<(B_ * S_ * H_ * 32) / 256, 256, 0, stream>>>(qkv, cost, sint);

    // 4. Attention (v2: register-blocked, 4 rows x 16-dim slice per thread)
    attn_kernel<<<dim3(B_ * H_, S_ / 256), 256, 0, stream>>>(qkv, att);

    // 5. Output projection + bias: [8192,1024] @ [1024,1024] + b_out
    sgemm_kernel<<<dim3(D_ / 128, ROWS_ / 128), 256, 0, stream>>>(
        att, w_out, out, ROWS_, D_, INNER_, b_out);
}